// Round 3
// baseline (66.246 us; speedup 1.0000x reference)
//
#include <hip/hip_runtime.h>

typedef _Float16 half8 __attribute__((ext_vector_type(8)));
typedef float    f32x4 __attribute__((ext_vector_type(4)));

#define DEV static __device__ __forceinline__

DEV unsigned short f2h(float f) {
  _Float16 h = (_Float16)f;
  return __builtin_bit_cast(unsigned short, h);
}
DEV float lrelu(float x) { return x > 0.f ? x : 0.01f * x; }
DEV f32x4 mfma16(half8 a, half8 b, f32x4 c) {
  return __builtin_amdgcn_mfma_f32_16x16x32_f16(a, b, c, 0, 0, 0);
}

// dims: B=4 N=256 H=768 D=200 NH=5 HD=40 OUT=12 ; padded K: head 320 (5*64), tail/P 224
// Inputs f32, output f32; intermediates fp16 (f32 accum).

// ---------------- prep: f32->fp16 casts + pad zeros + folded small precomputes ----------------
__global__ void __launch_bounds__(256) k_prep(
    const float* __restrict__ wr, const float* __restrict__ hw,
    const float* __restrict__ tw, const float* __restrict__ U,
    const float* __restrict__ W, const float* __restrict__ dw,
    unsigned short* __restrict__ wr16, unsigned short* __restrict__ hw16,
    unsigned short* __restrict__ tw16, unsigned short* __restrict__ headp,
    unsigned short* __restrict__ tail16, unsigned short* __restrict__ P16,
    unsigned short* __restrict__ DWhp, unsigned short* __restrict__ DWtp,
    float* __restrict__ biasH, float* __restrict__ biasT,
    float* __restrict__ DWs, unsigned short* __restrict__ Gp)
{
  int t = blockIdx.x * 256 + threadIdx.x;
  if (t < 196608) { // word_reps -> fp16 (4/thread)
    float4 v = reinterpret_cast<const float4*>(wr)[t];
    reinterpret_cast<uint2*>(wr16)[t] = make_uint2(
        (unsigned)f2h(v.x) | ((unsigned)f2h(v.y) << 16),
        (unsigned)f2h(v.z) | ((unsigned)f2h(v.w) << 16));
    return;
  }
  t -= 196608;
  if (t < 38400) { // head_w -> fp16
    float4 v = reinterpret_cast<const float4*>(hw)[t];
    reinterpret_cast<uint2*>(hw16)[t] = make_uint2(
        (unsigned)f2h(v.x) | ((unsigned)f2h(v.y) << 16),
        (unsigned)f2h(v.z) | ((unsigned)f2h(v.w) << 16));
    return;
  }
  t -= 38400;
  if (t < 38400) { // tail_w -> fp16
    float4 v = reinterpret_cast<const float4*>(tw)[t];
    reinterpret_cast<uint2*>(tw16)[t] = make_uint2(
        (unsigned)f2h(v.x) | ((unsigned)f2h(v.y) << 16),
        (unsigned)f2h(v.z) | ((unsigned)f2h(v.w) << 16));
    return;
  }
  t -= 38400;
  if (t < 6144) { // tail16 k-pad zeros [200,224)
    int r = t / 6, j = t % 6;
    *reinterpret_cast<uint2*>(tail16 + r * 224 + 200 + j * 4) = make_uint2(0u, 0u);
    return;
  }
  t -= 6144;
  if (t < 30720) { // headp x-pad zeros [40,64) per head-group
    int r = t / 30, rem = t % 30, h = rem / 6, j = rem % 6;
    *reinterpret_cast<uint2*>(headp + r * 320 + h * 64 + 40 + j * 4) = make_uint2(0u, 0u);
    return;
  }
  t -= 30720;
  if (t < 73728) { // P16 k-pad zeros [200,224)
    int row = t / 6, j = t % 6;
    *reinterpret_cast<uint2*>(P16 + row * 224 + 200 + j * 4) = make_uint2(0u, 0u);
    return;
  }
  t -= 73728;
  if (t < 3840) { // DWhp[o][kpos] = sum_kk dw[o,kk]*W[kk, h*40+x]  (x<40, else 0)
    int kpos = t / 12, o = t % 12;
    int h = kpos >> 6, x = kpos & 63;
    float acc = 0.f;
    if (x < 40) {
      int col = h * 40 + x;
      for (int kk = 0; kk < 200; ++kk) acc += dw[o * 200 + kk] * W[kk * 427 + col];
    }
    DWhp[o * 320 + kpos] = f2h(acc);
    return;
  }
  t -= 3840;
  if (t < 2688) { // DWtp[o][k] = sum_kk dw[o,kk]*W[kk, 201+k]  (k<200, else 0)
    int k = t / 12, o = t % 12;
    float acc = 0.f;
    if (k < 200) {
      for (int kk = 0; kk < 200; ++kk) acc += dw[o * 200 + kk] * W[kk * 427 + 201 + k];
    }
    DWtp[o * 224 + k] = f2h(acc);
    return;
  }
  t -= 2688;
  if (t < 24) { // ones-column biases: W[:,200] and W[:,401]
    int o = t % 12;
    int col = (t < 12) ? 200 : 401;
    float acc = 0.f;
    for (int kk = 0; kk < 200; ++kk) acc += dw[o * 200 + kk] * W[kk * 427 + col];
    if (t < 12) biasH[o] = acc; else biasT[o] = acc;
    return;
  }
  t -= 24;
  if (t < 300) { // DWs[o][s] = sum_kk dw[o,kk]*W[kk,402+s]
    int o = t / 25, s = t % 25;
    float acc = 0.f;
    for (int kk = 0; kk < 200; ++kk) acc += dw[o * 200 + kk] * W[kk * 427 + 402 + s];
    DWs[t] = acc;
    return;
  }
  t -= 300;
  if (t < 153600) { // Gp[h][c=o*40+y][x] = sum_d dw[o,h*40+d]*U[h,d,x,y] (x<40 else 0)
    int h = t / 30720, r1 = t % 30720;
    int x = r1 / 480, r2 = r1 % 480, o = r2 / 40, y = r2 % 40;
    float acc = 0.f;
    if (x < 40) {
      #pragma unroll 8
      for (int d = 0; d < 40; ++d)
        acc += dw[o * 200 + h * 40 + d] * U[((h * 40 + d) * 40 + x) * 40 + y];
    }
    Gp[(h * 480 + o * 40 + y) * 64 + x] = f2h(acc);
    return;
  }
}

// ---------------- GEMM1: [1024x768] x [400x768]^T -> leaky_relu -> headp/tail16 ----------------
__global__ void __launch_bounds__(64) k_gemm1(
    const unsigned short* __restrict__ wr16, const unsigned short* __restrict__ hw16,
    const unsigned short* __restrict__ tw16, const float* __restrict__ hb,
    const float* __restrict__ tb, unsigned short* __restrict__ headp,
    unsigned short* __restrict__ tail16)
{
  __shared__ __align__(16) unsigned short Xs[64 * 136];
  __shared__ __align__(16) unsigned short Wsh[64 * 136];
  int bid = blockIdx.x;
  int mt = bid / 7, nt = bid % 7;
  int lane = threadIdx.x, r15 = lane & 15, g8 = lane >> 4;
  int rb = mt * 64, cb = nt * 64;
  int c = cb + lane;

  f32x4 acc[4][4] = {};

  for (int kt = 0; kt < 6; ++kt) {
    int k0 = kt * 128;
    {
      const uint4* s = reinterpret_cast<const uint4*>(wr16 + (rb + lane) * 768 + k0);
      uint4* d = reinterpret_cast<uint4*>(&Xs[lane * 136]);
      #pragma unroll
      for (int j = 0; j < 16; ++j) d[j] = s[j];
    }
    {
      uint4* d = reinterpret_cast<uint4*>(&Wsh[lane * 136]);
      if (c < 200) {
        const uint4* s = reinterpret_cast<const uint4*>(hw16 + c * 768 + k0);
        #pragma unroll
        for (int j = 0; j < 16; ++j) d[j] = s[j];
      } else if (c < 400) {
        const uint4* s = reinterpret_cast<const uint4*>(tw16 + (c - 200) * 768 + k0);
        #pragma unroll
        for (int j = 0; j < 16; ++j) d[j] = s[j];
      } else {
        uint4 z = make_uint4(0u, 0u, 0u, 0u);
        #pragma unroll
        for (int j = 0; j < 16; ++j) d[j] = z;
      }
    }
    __syncthreads();
    #pragma unroll
    for (int ks = 0; ks < 4; ++ks) {
      half8 a[4], bb[4];
      #pragma unroll
      for (int g = 0; g < 4; ++g)
        a[g] = *reinterpret_cast<const half8*>(&Xs[(g * 16 + r15) * 136 + ks * 32 + g8 * 8]);
      #pragma unroll
      for (int h = 0; h < 4; ++h)
        bb[h] = *reinterpret_cast<const half8*>(&Wsh[(h * 16 + r15) * 136 + ks * 32 + g8 * 8]);
      #pragma unroll
      for (int g = 0; g < 4; ++g) {
        #pragma unroll
        for (int h = 0; h < 4; ++h)
          acc[g][h] = mfma16(a[g], bb[h], acc[g][h]);
      }
    }
    __syncthreads();
  }
  #pragma unroll
  for (int h = 0; h < 4; ++h) {
    int cc = cb + h * 16 + r15;
    if (cc >= 400) continue;
    float bias = (cc < 200) ? hb[cc] : tb[cc - 200];
    #pragma unroll
    for (int g = 0; g < 4; ++g) {
      #pragma unroll
      for (int q = 0; q < 4; ++q) {
        int m = rb + g * 16 + g8 * 4 + q;
        float val = lrelu(acc[g][h][q] + bias);
        if (cc < 200) headp[m * 320 + (cc / 40) * 64 + (cc % 40)] = f2h(val);
        else          tail16[m * 224 + (cc - 200)] = f2h(val);
      }
    }
  }
}

// ---------------- GEMM2: P (per head-group), A, Bt, E ----------------
__global__ void __launch_bounds__(64) k_gemm2(
    const unsigned short* __restrict__ headp, const unsigned short* __restrict__ tail16,
    const unsigned short* __restrict__ Gp, const unsigned short* __restrict__ DWhp,
    const unsigned short* __restrict__ DWtp, const float* __restrict__ biasH,
    const float* __restrict__ biasT, const float* __restrict__ se,
    const float* __restrict__ DWs, unsigned short* __restrict__ P16,
    float* __restrict__ A_ws, float* __restrict__ Bt_ws, float* __restrict__ E)
{
  __shared__ __align__(16) unsigned short sm[26240];
  int bid = blockIdx.x;
  int lane = threadIdx.x, r15 = lane & 15, g8 = lane >> 4;

  if (bid < 640) { // P: [1024 x 64]_h x [480 x 64]^T per head-group h
    int h = bid / 128, rem = bid % 128, mt = rem >> 3, nt = rem & 7;
    unsigned short* As = sm;
    unsigned short* Bs = sm + 64 * 72;
    {
      const uint4* s = reinterpret_cast<const uint4*>(headp + (mt * 64 + lane) * 320 + h * 64);
      uint4* d = reinterpret_cast<uint4*>(&As[lane * 72]);
      #pragma unroll
      for (int j = 0; j < 8; ++j) d[j] = s[j];
    }
    {
      int cc = nt * 64 + lane;
      uint4* d = reinterpret_cast<uint4*>(&Bs[lane * 72]);
      if (cc < 480) {
        const uint4* s = reinterpret_cast<const uint4*>(Gp + (h * 480 + cc) * 64);
        #pragma unroll
        for (int j = 0; j < 8; ++j) d[j] = s[j];
      } else {
        uint4 z = make_uint4(0u, 0u, 0u, 0u);
        #pragma unroll
        for (int j = 0; j < 8; ++j) d[j] = z;
      }
    }
    __syncthreads();
    f32x4 acc[4][4] = {};
    #pragma unroll
    for (int ks = 0; ks < 2; ++ks) {
      half8 a[4], bb[4];
      #pragma unroll
      for (int g = 0; g < 4; ++g)
        a[g] = *reinterpret_cast<const half8*>(&As[(g * 16 + r15) * 72 + ks * 32 + g8 * 8]);
      #pragma unroll
      for (int hh = 0; hh < 4; ++hh)
        bb[hh] = *reinterpret_cast<const half8*>(&Bs[(hh * 16 + r15) * 72 + ks * 32 + g8 * 8]);
      #pragma unroll
      for (int g = 0; g < 4; ++g) {
        #pragma unroll
        for (int hh = 0; hh < 4; ++hh)
          acc[g][hh] = mfma16(a[g], bb[hh], acc[g][hh]);
      }
    }
    #pragma unroll
    for (int hh = 0; hh < 4; ++hh) {
      int cc = nt * 64 + hh * 16 + r15;
      if (cc >= 480) continue;
      int o = cc / 40, y = cc % 40;
      #pragma unroll
      for (int g = 0; g < 4; ++g) {
        #pragma unroll
        for (int q = 0; q < 4; ++q) {
          int r = mt * 64 + g * 16 + g8 * 4 + q;
          P16[(r * 12 + o) * 224 + h * 40 + y] = f2h(acc[g][hh][q]);
        }
      }
    }
  } else if (bid < 656) { // A: [1024 x 320] x [12(16) x 320]^T
    int mt = bid - 640;
    unsigned short* As = sm;
    unsigned short* Bs = sm + 64 * 328;
    {
      const uint4* s = reinterpret_cast<const uint4*>(headp + (mt * 64 + lane) * 320);
      uint4* d = reinterpret_cast<uint4*>(&As[lane * 328]);
      #pragma unroll
      for (int j = 0; j < 40; ++j) d[j] = s[j];
    }
    #pragma unroll
    for (int tt = 0; tt < 10; ++tt) {
      int idx = tt * 64 + lane;
      int row = idx / 40, j = idx % 40;
      uint4 v = make_uint4(0u, 0u, 0u, 0u);
      if (row < 12) v = reinterpret_cast<const uint4*>(DWhp + row * 320)[j];
      reinterpret_cast<uint4*>(&Bs[row * 328])[j] = v;
    }
    __syncthreads();
    f32x4 acc[4] = {};
    #pragma unroll
    for (int ks = 0; ks < 10; ++ks) {
      half8 bb = *reinterpret_cast<const half8*>(&Bs[r15 * 328 + ks * 32 + g8 * 8]);
      #pragma unroll
      for (int g = 0; g < 4; ++g) {
        half8 a = *reinterpret_cast<const half8*>(&As[(g * 16 + r15) * 328 + ks * 32 + g8 * 8]);
        acc[g] = mfma16(a, bb, acc[g]);
      }
    }
    if (r15 < 12) {
      float bv = biasH[r15];
      #pragma unroll
      for (int g = 0; g < 4; ++g) {
        #pragma unroll
        for (int q = 0; q < 4; ++q) {
          int r = mt * 64 + g * 16 + g8 * 4 + q;
          A_ws[((r >> 8) * 12 + r15) * 256 + (r & 255)] = acc[g][q] + bv;
        }
      }
    }
  } else if (bid < 672) { // Bt: [1024 x 224] x [12(16) x 224]^T
    int mt = bid - 656;
    unsigned short* As = sm;
    unsigned short* Bs = sm + 64 * 232;
    {
      const uint4* s = reinterpret_cast<const uint4*>(tail16 + (mt * 64 + lane) * 224);
      uint4* d = reinterpret_cast<uint4*>(&As[lane * 232]);
      #pragma unroll
      for (int j = 0; j < 28; ++j) d[j] = s[j];
    }
    #pragma unroll
    for (int tt = 0; tt < 7; ++tt) {
      int idx = tt * 64 + lane;
      int row = idx / 28, j = idx % 28;
      uint4 v = make_uint4(0u, 0u, 0u, 0u);
      if (row < 12) v = reinterpret_cast<const uint4*>(DWtp + row * 224)[j];
      reinterpret_cast<uint4*>(&Bs[row * 232])[j] = v;
    }
    __syncthreads();
    f32x4 acc[4] = {};
    #pragma unroll
    for (int ks = 0; ks < 7; ++ks) {
      half8 bb = *reinterpret_cast<const half8*>(&Bs[r15 * 232 + ks * 32 + g8 * 8]);
      #pragma unroll
      for (int g = 0; g < 4; ++g) {
        half8 a = *reinterpret_cast<const half8*>(&As[(g * 16 + r15) * 232 + ks * 32 + g8 * 8]);
        acc[g] = mfma16(a, bb, acc[g]);
      }
    }
    if (r15 < 12) {
      float bv = biasT[r15];
      #pragma unroll
      for (int g = 0; g < 4; ++g) {
        #pragma unroll
        for (int q = 0; q < 4; ++q) {
          int r = mt * 64 + g * 16 + g8 * 4 + q;
          Bt_ws[((r >> 8) * 12 + r15) * 256 + (r & 255)] = acc[g][q] + bv;
        }
      }
    }
  } else { // E[o][p] = sum_s DWs[o,s]*se[p,s]
    int t2 = (bid - 672) * 64 + lane;
    if (t2 < 360) {
      int o = t2 / 30, p = t2 % 30;
      float acc = 0.f;
      #pragma unroll
      for (int s = 0; s < 25; ++s) acc += DWs[o * 25 + s] * se[p * 25 + s];
      E[t2] = acc;
    }
  }
}

// ---------------- main: out[b,o,m,n] = P(m,:)·tail(n,:) + A[m] + Bt[n] + E[span] + db ----------------
__global__ void __launch_bounds__(64) k_main(
    const unsigned short* __restrict__ P16, const unsigned short* __restrict__ tail16,
    const float* __restrict__ A_ws, const float* __restrict__ Bt_ws,
    const float* __restrict__ E, const float* __restrict__ db,
    float* __restrict__ out)
{
  __shared__ __align__(16) unsigned short Ps[64 * 232];
  __shared__ __align__(16) unsigned short Ts[64 * 232];
  int bid = blockIdx.x;
  int nt = bid & 3, mt = (bid >> 2) & 3, bo = bid >> 4;
  int o = bo % 12, b = bo / 12;
  int lane = threadIdx.x, r15 = lane & 15, g8 = lane >> 4;
  {
    const uint4* s = reinterpret_cast<const uint4*>(P16 + ((b * 256 + mt * 64 + lane) * 12 + o) * 224);
    uint4* d = reinterpret_cast<uint4*>(&Ps[lane * 232]);
    #pragma unroll
    for (int j = 0; j < 28; ++j) d[j] = s[j];
    const uint4* s2 = reinterpret_cast<const uint4*>(tail16 + (b * 256 + nt * 64 + lane) * 224);
    uint4* d2 = reinterpret_cast<uint4*>(&Ts[lane * 232]);
    #pragma unroll
    for (int j = 0; j < 28; ++j) d2[j] = s2[j];
  }
  __syncthreads();
  f32x4 acc[4][4] = {};
  #pragma unroll
  for (int ks = 0; ks < 7; ++ks) {
    half8 a[4], bb[4];
    #pragma unroll
    for (int g = 0; g < 4; ++g)
      a[g] = *reinterpret_cast<const half8*>(&Ps[(g * 16 + r15) * 232 + ks * 32 + g8 * 8]);
    #pragma unroll
    for (int h = 0; h < 4; ++h)
      bb[h] = *reinterpret_cast<const half8*>(&Ts[(h * 16 + r15) * 232 + ks * 32 + g8 * 8]);
    #pragma unroll
    for (int g = 0; g < 4; ++g) {
      #pragma unroll
      for (int h = 0; h < 4; ++h)
        acc[g][h] = mfma16(a[g], bb[h], acc[g][h]);
    }
  }
  const float dbv = db[o];
  const float* Arow = A_ws + (b * 12 + o) * 256;
  const float* Btrow = Bt_ws + (b * 12 + o) * 256;
  const float* Erow = E + o * 30;
  #pragma unroll
  for (int g = 0; g < 4; ++g) {
    #pragma unroll
    for (int q = 0; q < 4; ++q) {
      int m = mt * 64 + g * 16 + g8 * 4 + q;
      float am = Arow[m] + dbv;
      #pragma unroll
      for (int h = 0; h < 4; ++h) {
        int n = nt * 64 + h * 16 + r15;
        int dpos = n - m;
        dpos = (dpos < -15) ? -15 : (dpos > 14 ? 14 : dpos);
        out[((b * 12 + o) * 256 + m) * 256 + n] = acc[g][h][q] + am + Btrow[n] + Erow[dpos + 15];
      }
    }
  }
}

extern "C" void kernel_launch(void* const* d_in, const int* in_sizes, int n_in,
                              void* d_out, int out_size, void* d_ws, size_t ws_size,
                              hipStream_t stream) {
  (void)in_sizes; (void)n_in; (void)out_size; (void)ws_size;
  const float* wr = (const float*)d_in[0];
  const float* hw = (const float*)d_in[4];
  const float* hb = (const float*)d_in[5];
  const float* tw = (const float*)d_in[6];
  const float* tb = (const float*)d_in[7];
  const float* U  = (const float*)d_in[8];
  const float* se = (const float*)d_in[9];
  const float* W  = (const float*)d_in[10];
  const float* dw = (const float*)d_in[11];
  const float* db = (const float*)d_in[12];

  char* ws = (char*)d_ws;
  unsigned short* wr16   = (unsigned short*)(ws + 0);        // 1,572,864 B
  unsigned short* hw16   = (unsigned short*)(ws + 1572864);  //   307,200
  unsigned short* tw16   = (unsigned short*)(ws + 1880064);  //   307,200
  unsigned short* headp  = (unsigned short*)(ws + 2187264);  //   655,360  [1024][320]
  unsigned short* tail16 = (unsigned short*)(ws + 2842624);  //   458,752  [1024][224]
  unsigned short* P16    = (unsigned short*)(ws + 3301376);  // 5,505,024  [1024*12][224]
  float* A_ws            = (float*)(ws + 8806400);           //    49,152
  float* Bt_ws           = (float*)(ws + 8855552);           //    49,152
  unsigned short* DWhp   = (unsigned short*)(ws + 8904704);  //     7,680
  unsigned short* DWtp   = (unsigned short*)(ws + 8912384);  //     5,376
  float* biasH           = (float*)(ws + 8917760);           //        64
  float* biasT           = (float*)(ws + 8917824);           //        64
  float* E_ws            = (float*)(ws + 8917888);           //     1,440
  float* DWs             = (float*)(ws + 8919328);           //     1,200
  unsigned short* Gp     = (unsigned short*)(ws + 8920528);  //   307,200  -> end ~9.23 MB

  k_prep<<<2127, 256, 0, stream>>>(wr, hw, tw, U, W, dw,
                                   wr16, hw16, tw16, headp, tail16, P16,
                                   DWhp, DWtp, biasH, biasT, DWs, Gp);
  k_gemm1<<<112, 64, 0, stream>>>(wr16, hw16, tw16, hb, tb, headp, tail16);
  k_gemm2<<<678, 64, 0, stream>>>(headp, tail16, Gp, DWhp, DWtp, biasH, biasT,
                                  se, DWs, P16, A_ws, Bt_ws, E_ws);
  k_main<<<768, 64, 0, stream>>>(P16, tail16, A_ws, Bt_ws, E_ws, db,
                                 (float*)d_out);
}